// Round 5
// baseline (296.910 us; speedup 1.0000x reference)
//
#include <hip/hip_runtime.h>

#define NXD 512
#define NYD 512
#define CD  64
#define NPIX (NXD * NYD)
// Problem constants fixed by the reference: B=4, C=64, NX=NY=512.
//
// Window decomposition (measured via rocprof): harness poisons the 1 GiB
// workspace (166-172 us @ 6.3 TB/s) + 268 MB output (~42 us) INSIDE the timed
// window => ~210 us fixed. Kernel-side share ~= headline - 210. Total window
// HBM traffic ~1.64 GB => 256 us absolute floor. Compare kernel dispatch
// times, not headline dur_us.
//
// Theory ledger:
//   R5 (2 quads/thread, +2^23 apart):  NEUTRAL (289->293) - not latency/MLP.
//   R6 (16-wave channel groups, L1):   NEUTRAL (293->299) - not read traffic.
//   R7 (persistent, reg winners, x32): REGRESSED (->345) - scattered write
//       front + vmcnt saturation. Reverted.
//   R8 (4-ch groups, float4 gathers):  NEUTRAL (->290.5) - not address-pipe
//       issue density (4x fewer VMEM insts/byte changed nothing).
//   R9 (this): the NT flag itself. Every prior variant kept
//       __builtin_nontemporal_store; its rationale (protect winner/feat in
//       L2) was VOIDED by R6's null result. NT bypasses L2/L3, cutting the
//       256 MiB L3 - which fits the whole 268 MB output and is the fill's
//       write path - out of the pipeline. fillBufferAligned (normal
//       dwordx4 stores, same 64x16B contiguous pattern) sustains 6.4 TB/s
//       vs our 3.9 TB/s. Single-variable A/B: R0 structure, plain stores.
//
// Round-3 lesson (measured): per-instruction 16B/lane contiguous stores +
// linear block-order streams are mandatory (R3's per-lane channel sweep
// regressed 79->155 us). R9 keeps the exact R0 linear mapping.

typedef float nfloat4 __attribute__((ext_vector_type(4)));

// Init winner array to -1 (int4 stores). 4 MiB.
__global__ void ppscatter_init_winner(int4* __restrict__ win4, int n_win4) {
    int i = blockIdx.x * blockDim.x + threadIdx.x;
    if (i < n_win4) win4[i] = make_int4(-1, -1, -1, -1);
}

// Last-write-wins vote: max voxel index per flat slot wins (matches numpy
// fancy-assignment last-duplicate-wins; verified absmax=0.0 rounds 1-8).
__global__ void ppscatter_vote(const int* __restrict__ coords, int n,
                               int* __restrict__ winner) {
    int v = blockIdx.x * blockDim.x + threadIdx.x;
    if (v >= n) return;
    int b = coords[3 * v + 0];
    int x = coords[3 * v + 1];
    int y = coords[3 * v + 2];
    atomicMax(&winner[b * NPIX + x * NYD + y], v);
}

// Gather: one thread per output float4, linear mapping (i -> out4[i]).
//   i bits: y4 [0:6], x [7:15], c [16:21], b [22:23].
// Stores: 1 KB/wave, fully contiguous across the grid (streaming-optimal),
// and PLAIN (cached) so the write stream rides L2/L3 write-combining like
// the 6.4 TB/s fill does. (NT bypass measured-irrelevant for reads per R6,
// and is the prime suspect for the 3.9 vs 6.4 TB/s store gap.)
__global__ void ppscatter_gather(const float* __restrict__ feat,
                                 const int* __restrict__ winner,
                                 nfloat4* __restrict__ out4) {
    int i = blockIdx.x * blockDim.x + threadIdx.x;  // 16,777,216 threads
    int c  = (i >> 16) & 63;
    int b  = i >> 22;

    const int4* win4 = (const int4*)winner;
    int4 w = win4[(b << 16) | (i & 0xFFFF)];        // winner[b][x][4*y4 ..]

    nfloat4 val = {0.f, 0.f, 0.f, 0.f};
    // Empty fast path: entries are -1 or >=0; AND == -1 iff all empty (~74%).
    if ((w.x & w.y & w.z & w.w) != -1) {
        if (w.x >= 0) val.x = feat[(w.x << 6) + c];
        if (w.y >= 0) val.y = feat[(w.y << 6) + c];
        if (w.z >= 0) val.z = feat[(w.z << 6) + c];
        if (w.w >= 0) val.w = feat[(w.w << 6) + c];
    }
    out4[i] = val;
}

extern "C" void kernel_launch(void* const* d_in, const int* in_sizes, int n_in,
                              void* d_out, int out_size, void* d_ws, size_t ws_size,
                              hipStream_t stream) {
    const float* feat  = (const float*)d_in[0];
    const int* coords  = (const int*)d_in[1];

    int n = in_sizes[1] / 3;            // 80000 voxels
    int* winner = (int*)d_ws;           // B*NX*NY ints = 4 MiB scratch

    const int T = 256;
    int B = out_size / (CD * NPIX);     // 4

    int n_win4 = (B * NPIX) / 4;        // 262144
    ppscatter_init_winner<<<(n_win4 + T - 1) / T, T, 0, stream>>>((int4*)winner, n_win4);

    ppscatter_vote<<<(n + T - 1) / T, T, 0, stream>>>(coords, n, winner);

    int n_out4 = out_size / 4;          // 16,777,216
    ppscatter_gather<<<n_out4 / T, T, 0, stream>>>(feat, winner, (nfloat4*)d_out);
}